// Round 6
// baseline (92.503 us; speedup 1.0000x reference)
//
#include <hip/hip_runtime.h>
#include <hip/hip_fp16.h>
#include <math.h>

#define N_SAMPLES 131072
#define HIDDEN    256
#define M_GRID    2048
#define REC       72           // floats per table record (288B; 16B-aligned)
#define U_LO      (-8.0f)
#define DELTA     0.0078125f   // 16 / 2048
#define INV_DELTA 128.0f
#define MT3       8            // m-tile of the layer-3 kernel (256 blocks)
#define STR2      69           // dword stride of packed fp16 weight tiles

// Record layout (72 floats / 288 B):
//   float ofs 0..7  : 16 fp16 knots cw[0..15]  (search-only; cw[16]=5 implicit)
//   float ofs 8+4k  : uint4 chunk k = {h2(ch[k],ch[k+1]), h2(dv[k],dv[k+1]),
//                                      h2(lam[k],cw[k]),  h2(cw[k+1],0)}
__device__ __attribute__((aligned(16))) float g_H2T[M_GRID * HIDDEN];  // [m][k], 2 MB
__device__ __attribute__((aligned(16))) float g_table[M_GRID * REC];   // 576 KB
__device__ __attribute__((aligned(16))) float g_knots0[REC];

__device__ __forceinline__ float rcpf(float x) { return __builtin_amdgcn_rcpf(x); }

__device__ __forceinline__ float softplusf(float x) {
  return fmaxf(x, 0.0f) + log1pf(expf(-fabsf(x)));
}

__device__ __forceinline__ unsigned int packh2(float a, float b) {
  __half2 h = __floats2half2_rn(a, b);
  return *(unsigned int*)&h;
}

__device__ __forceinline__ void unpack8(uint4 u, float* f) {
  float2 t;
  t = __half22float2(*(__half2*)&u.x); f[0] = t.x; f[1] = t.y;
  t = __half22float2(*(__half2*)&u.y); f[2] = t.x; f[3] = t.y;
  t = __half22float2(*(__half2*)&u.z); f[4] = t.x; f[5] = t.y;
  t = __half22float2(*(__half2*)&u.w); f[6] = t.x; f[7] = t.y;
}

// 16-lane-parallel spline-param processing (lane kl of a 16-lane group = bin kl).
__device__ __forceinline__ void process16(float wv, float hv, float dvr,
                                          float lamv, int kl,
                                          float* __restrict__ rec) {
  // ---- widths: softmax + prefix -> cw[kl], cw[kl+1] ----
  float mx = wv;
#pragma unroll
  for (int d = 1; d < 16; d <<= 1) mx = fmaxf(mx, __shfl_xor(mx, d, 16));
  float v = expf(wv - mx);
  float s = v;
#pragma unroll
  for (int d = 1; d < 16; d <<= 1) s += __shfl_xor(s, d, 16);
  float inc = fmaf(v, 0.984f * rcpf(s), 0.001f);
  float cum = inc;
#pragma unroll
  for (int d = 1; d < 16; d <<= 1) {
    float n = __shfl_up(cum, d, 16);
    if (kl >= d) cum += n;
  }
  float cwk1 = (kl == 15) ? 5.0f : fmaf(cum, 10.0f, -5.0f);
  float cwk = __shfl_up(cwk1, 1, 16);
  if (kl == 0) cwk = -5.0f;
  // ---- heights ----
  float mh = hv;
#pragma unroll
  for (int d = 1; d < 16; d <<= 1) mh = fmaxf(mh, __shfl_xor(mh, d, 16));
  float vh = expf(hv - mh);
  float sh = vh;
#pragma unroll
  for (int d = 1; d < 16; d <<= 1) sh += __shfl_xor(sh, d, 16);
  float inch = fmaf(vh, 0.984f * rcpf(sh), 0.001f);
  float cumh = inch;
#pragma unroll
  for (int d = 1; d < 16; d <<= 1) {
    float n = __shfl_up(cumh, d, 16);
    if (kl >= d) cumh += n;
  }
  float chk1 = (kl == 15) ? 5.0f : fmaf(cumh, 10.0f, -5.0f);
  float chk = __shfl_up(chk1, 1, 16);
  if (kl == 0) chk = -5.0f;
  // ---- derivatives (boundary = 1) ----
  float dvk1 = (kl < 15) ? (0.001f + softplusf(dvr)) : 1.0f;
  float dvk = __shfl_up(dvk1, 1, 16);
  if (kl == 0) dvk = 1.0f;
  // ---- lambda ----
  float lm = fmaf(0.95f, 1.0f / (1.0f + expf(-lamv)), 0.025f);
  // ---- emit chunk kl ----
  uint4 ck = make_uint4(packh2(chk, chk1), packh2(dvk, dvk1),
                        packh2(lm, cwk), packh2(cwk1, 0.0f));
  ((uint4*)rec)[2 + kl] = ck;
  // ---- knot row: dword q = h2(cw[2q], cw[2q+1]), lanes 0..7 ----
  float cA = __shfl(cwk, 2 * kl, 16);
  float cB = __shfl(cwk, 2 * kl + 1, 16);
  if (kl < 8) ((unsigned int*)rec)[kl] = packh2(cA, cB);
}

// Monotonic linear-rational spline (approx rcp/sqrt; tol 0.099 >> 1ulp).
__device__ __forceinline__ float spline_eval(float z, float xk, float xk1,
                                             float yk, float yk1,
                                             float dk, float dk1, float lam) {
  float xc = fminf(fmaxf(z, -5.0f), 5.0f);
  float wk = xk1 - xk;
  float hk = yk1 - yk;
  float wb = __builtin_amdgcn_sqrtf(dk * rcpf(dk1));
  float wc = fmaf(lam, dk, (1.0f - lam) * wb * dk1) * wk * rcpf(hk);
  float ya = yk;
  float yb = yk + hk;
  float yc = fmaf(lam * wb, yb, (1.0f - lam) * ya) * rcpf(fmaf(lam, wb, 1.0f - lam));
  float th = (xc - xk) * rcpf(wk);
  bool left = th <= lam;
  float num = left ? fmaf(ya, lam - th, wc * yc * th)
                   : fmaf(wc * yc, 1.0f - th, wb * yb * (th - lam));
  float den = left ? fmaf(wc, th, lam - th)
                   : fmaf(wc, 1.0f - th, wb * (th - lam));
  float y = num * rcpf(den);
  bool inside = (z >= -5.0f) && (z <= 5.0f);
  return inside ? y : z;
}

// dim-1 step: knot quads pre-loaded by caller (issued early to hide latency).
__device__ __forceinline__ float dim1_eval(float z1, const float* __restrict__ r0,
                                           float f, uint4 q0, uint4 q1) {
  float kf[16];
  unpack8(q0, kf);
  unpack8(q1, kf + 8);
  float xc1 = fminf(fmaxf(z1, -5.0f), 5.0f);
  int k1 = 0;
#pragma unroll
  for (int j = 1; j < 16; j++) k1 += (xc1 >= kf[j]) ? 1 : 0;
  const float* c0 = r0 + 8 + 4 * k1;
  uint4 A = *(const uint4*)c0;
  uint4 B = *(const uint4*)(c0 + REC);
  float2 Ay = __half22float2(*(__half2*)&A.x);
  float2 Ad = __half22float2(*(__half2*)&A.y);
  float2 Al = __half22float2(*(__half2*)&A.z);
  float2 Ax = __half22float2(*(__half2*)&A.w);
  float2 By = __half22float2(*(__half2*)&B.x);
  float2 Bd = __half22float2(*(__half2*)&B.y);
  float2 Bl = __half22float2(*(__half2*)&B.z);
  float2 Bx = __half22float2(*(__half2*)&B.w);
  float yk  = fmaf(f, By.x - Ay.x, Ay.x);
  float yk1 = fmaf(f, By.y - Ay.y, Ay.y);
  float dk  = fmaf(f, Bd.x - Ad.x, Ad.x);
  float dk1 = fmaf(f, Bd.y - Ad.y, Ad.y);
  float lam = fmaf(f, Bl.x - Al.x, Al.x);
  float xk  = fmaf(f, Bl.y - Al.y, Al.y);
  float xk1 = fmaf(f, Bx.x - Ax.x, Ax.x);
  return spline_eval(z1, xk, xk1, yk, yk1, dk, dk1, lam);
}

// dim-0 step: constant knots (registers) + chunk from LDS.
__device__ __forceinline__ float dim0_eval(float z0, const float* __restrict__ kn0,
                                           const float* __restrict__ kf0) {
  float xc0 = fminf(fmaxf(z0, -5.0f), 5.0f);
  int k0 = 0;
#pragma unroll
  for (int j = 1; j < 16; j++) k0 += (xc0 >= kf0[j]) ? 1 : 0;
  uint4 C = *(const uint4*)&kn0[8 + 4 * k0];
  float2 Cy = __half22float2(*(__half2*)&C.x);
  float2 Cd = __half22float2(*(__half2*)&C.y);
  float2 Cl = __half22float2(*(__half2*)&C.z);
  float2 Cx = __half22float2(*(__half2*)&C.w);
  return spline_eval(z0, Cl.y, Cx.x, Cy.x, Cy.y, Cd.x, Cd.y, Cl.x);
}

// ---------------- Layer-2 GEMM: H2T[m][o] = relu(sum_k W2[o][k]*h_k(u_m) + b2[o])
__global__ __launch_bounds__(256) void k_gemm2(const float* __restrict__ W1,
                                               const float* __restrict__ b1,
                                               const float* __restrict__ W2,
                                               const float* __restrict__ b2) {
  __shared__ unsigned int sW[128 * STR2];  // 35.3 KB
  __shared__ float2 sAB[256];              // 2 KB
  __shared__ float red[3 * 64 * 36];       // 27.6 KB
  const int t = threadIdx.x;
  const int m0 = blockIdx.x * 32;
  const int o0 = blockIdx.y * 64;
  {
    const int ol = t >> 2, seg = t & 3;
    const float* src = W2 + (size_t)(o0 + ol) * 256 + 16 * seg;
#pragma unroll
    for (int c = 0; c < 4; c++) {
#pragma unroll
      for (int q = 0; q < 4; q++) {
        float4 v = *(const float4*)(src + 64 * c + 4 * q);
        const int k2 = (64 * c + 16 * seg + 4 * q) >> 1;
        sW[(k2 + 0) * STR2 + ol] = packh2(v.x, v.y);
        sW[(k2 + 1) * STR2 + ol] = packh2(v.z, v.w);
      }
    }
  }
  sAB[t] = make_float2(W1[2 * t], b1[t]);
  __syncthreads();
  const int w = t >> 6, lane = t & 63;
  const int tp = lane >> 2, tm = lane & 3;
  const float u0 = fmaf((float)(m0 + 8 * tm), DELTA, U_LO);
  float acc[4][8] = {};
  const int kb2 = w * 32;
#pragma unroll 4
  for (int kk = 0; kk < 32; kk++) {
    const int k2 = kb2 + kk;
    uint4 ap = *(const uint4*)&sW[k2 * STR2 + 4 * tp];
    float2 a0 = __half22float2(*(__half2*)&ap.x);
    float2 a1 = __half22float2(*(__half2*)&ap.y);
    float2 a2 = __half22float2(*(__half2*)&ap.z);
    float2 a3 = __half22float2(*(__half2*)&ap.w);
    float2 abe = sAB[2 * k2];
    float2 abo = sAB[2 * k2 + 1];
    float t0e = fmaf(abe.x, u0, abe.y), ste = abe.x * DELTA;
    float t0o = fmaf(abo.x, u0, abo.y), sto = abo.x * DELTA;
    float he[8], ho[8];
#pragma unroll
    for (int j = 0; j < 8; j++) {
      he[j] = fmaxf(fmaf((float)j, ste, t0e), 0.0f);
      ho[j] = fmaxf(fmaf((float)j, sto, t0o), 0.0f);
    }
#pragma unroll
    for (int j = 0; j < 8; j++) {
      acc[0][j] = fmaf(a0.x, he[j], acc[0][j]);
      acc[1][j] = fmaf(a1.x, he[j], acc[1][j]);
      acc[2][j] = fmaf(a2.x, he[j], acc[2][j]);
      acc[3][j] = fmaf(a3.x, he[j], acc[3][j]);
      acc[0][j] = fmaf(a0.y, ho[j], acc[0][j]);
      acc[1][j] = fmaf(a1.y, ho[j], acc[1][j]);
      acc[2][j] = fmaf(a2.y, ho[j], acc[2][j]);
      acc[3][j] = fmaf(a3.y, ho[j], acc[3][j]);
    }
  }
  if (w > 0) {
#pragma unroll
    for (int i = 0; i < 4; i++) {
      *(float4*)&red[((w - 1) * 64 + lane) * 36 + 8 * i] =
          make_float4(acc[i][0], acc[i][1], acc[i][2], acc[i][3]);
      *(float4*)&red[((w - 1) * 64 + lane) * 36 + 8 * i + 4] =
          make_float4(acc[i][4], acc[i][5], acc[i][6], acc[i][7]);
    }
  }
  __syncthreads();
  if (w == 0) {
#pragma unroll
    for (int v = 0; v < 3; v++) {
#pragma unroll
      for (int i = 0; i < 4; i++) {
        float4 r0 = *(const float4*)&red[(v * 64 + lane) * 36 + 8 * i];
        float4 r1 = *(const float4*)&red[(v * 64 + lane) * 36 + 8 * i + 4];
        acc[i][0] += r0.x; acc[i][1] += r0.y; acc[i][2] += r0.z; acc[i][3] += r0.w;
        acc[i][4] += r1.x; acc[i][5] += r1.y; acc[i][6] += r1.z; acc[i][7] += r1.w;
      }
    }
    float4 bb = *(const float4*)&b2[o0 + 4 * tp];
#pragma unroll
    for (int j = 0; j < 8; j++) {
      float4 r;
      r.x = fmaxf(acc[0][j] + bb.x, 0.0f);
      r.y = fmaxf(acc[1][j] + bb.y, 0.0f);
      r.z = fmaxf(acc[2][j] + bb.z, 0.0f);
      r.w = fmaxf(acc[3][j] + bb.w, 0.0f);
      *(float4*)&g_H2T[(size_t)(m0 + 8 * tm + j) * 256 + o0 + 4 * tp] = r;
    }
  }
}

// ---------------- Layer-3 GEMM (odd rows of W3) + PARALLEL param processing
__global__ __launch_bounds__(256) void k_gemm3proc(const float* __restrict__ W3,
                                                   const float* __restrict__ b3) {
  __shared__ unsigned int sW[128 * STR2];  // 35.3 KB packed W3odd^T [k2][p]
  __shared__ unsigned int sH[128 * 9];     // 4.6 KB packed H2 slice [k2][m]
  __shared__ float red[3 * 64 * 8];        // 6 KB wave partials
  __shared__ float raws[64 * 9];           // 2.3 KB [p][m]
  const int t = threadIdx.x;
  const int m0 = blockIdx.x * MT3;
  {
    const int ol = t >> 2, seg = t & 3;
    const int row = (ol < 63) ? (2 * ol + 1) : 1;
    const float* src = W3 + (size_t)row * 256 + 16 * seg;
#pragma unroll
    for (int c = 0; c < 4; c++) {
#pragma unroll
      for (int q = 0; q < 4; q++) {
        float4 v = *(const float4*)(src + 64 * c + 4 * q);
        const int k2 = (64 * c + 16 * seg + 4 * q) >> 1;
        sW[(k2 + 0) * STR2 + ol] = packh2(v.x, v.y);
        sW[(k2 + 1) * STR2 + ol] = packh2(v.z, v.w);
      }
    }
  }
  {
    const int j = t & 7, c = t >> 3;
    const float* src = g_H2T + (size_t)(m0 + j) * 256 + 8 * c;
    float4 f0 = *(const float4*)(src);
    float4 f1 = *(const float4*)(src + 4);
    sH[(4 * c + 0) * 9 + j] = packh2(f0.x, f0.y);
    sH[(4 * c + 1) * 9 + j] = packh2(f0.z, f0.w);
    sH[(4 * c + 2) * 9 + j] = packh2(f1.x, f1.y);
    sH[(4 * c + 3) * 9 + j] = packh2(f1.z, f1.w);
  }
  __syncthreads();
  const int w = t >> 6, lane = t & 63;
  const int tp = lane >> 2, tm = lane & 3;
  float acc[4][2] = {};
  const int kb2 = w * 32;
#pragma unroll 4
  for (int kk = 0; kk < 32; kk++) {
    const int k2 = kb2 + kk;
    uint4 ap = *(const uint4*)&sW[k2 * STR2 + 4 * tp];
    uint2 bp = *(const uint2*)&sH[k2 * 9 + 2 * tm];
    float2 a0 = __half22float2(*(__half2*)&ap.x);
    float2 a1 = __half22float2(*(__half2*)&ap.y);
    float2 a2 = __half22float2(*(__half2*)&ap.z);
    float2 a3 = __half22float2(*(__half2*)&ap.w);
    float2 b0 = __half22float2(*(__half2*)&bp.x);
    float2 b1v = __half22float2(*(__half2*)&bp.y);
    float ae[4] = {a0.x, a1.x, a2.x, a3.x};
    float ao[4] = {a0.y, a1.y, a2.y, a3.y};
#pragma unroll
    for (int i = 0; i < 4; i++) {
      acc[i][0] = fmaf(ae[i], b0.x, acc[i][0]);
      acc[i][0] = fmaf(ao[i], b0.y, acc[i][0]);
      acc[i][1] = fmaf(ae[i], b1v.x, acc[i][1]);
      acc[i][1] = fmaf(ao[i], b1v.y, acc[i][1]);
    }
  }
  // (no barrier needed here: red is a distinct buffer; the barrier below
  //  orders the w>0 writes against the w==0 reads)
  if (w > 0) {
#pragma unroll
    for (int i = 0; i < 4; i++) {
      red[((w - 1) * 64 + lane) * 8 + 2 * i + 0] = acc[i][0];
      red[((w - 1) * 64 + lane) * 8 + 2 * i + 1] = acc[i][1];
    }
  }
  __syncthreads();
  if (w == 0) {
#pragma unroll
    for (int v = 0; v < 3; v++) {
#pragma unroll
      for (int i = 0; i < 4; i++) {
        acc[i][0] += red[(v * 64 + lane) * 8 + 2 * i + 0];
        acc[i][1] += red[(v * 64 + lane) * 8 + 2 * i + 1];
      }
    }
#pragma unroll
    for (int i = 0; i < 4; i++) {
      const int p = 4 * tp + i;
      const int bi = (p < 63) ? (2 * p + 1) : 1;
      const float bias = b3[bi];
      raws[p * 9 + 2 * tm + 0] = acc[i][0] + bias;
      raws[p * 9 + 2 * tm + 1] = acc[i][1] + bias;
    }
  }
  __syncthreads();
  if (t < 128) {
    const int c = t >> 4, kl = t & 15;
    float wv = raws[kl * 9 + c];
    float hv = raws[(16 + kl) * 9 + c];
    float dvr = raws[(32 + kl) * 9 + c];
    float lamv = raws[(47 + kl) * 9 + c];
    process16(wv, hv, dvr, lamv, kl, g_table + (size_t)(m0 + c) * REC);
  } else if (blockIdx.x == 0 && (t >> 4) == 8) {
    const int kl = t & 15;
    float wv = b3[2 * kl];
    float hv = b3[2 * (16 + kl)];
    float dvr = b3[2 * (32 + kl)];
    float lamv = b3[2 * (47 + kl)];
    process16(wv, hv, dvr, lamv, kl, g_knots0);
  }
}

// ---------------- Main flow kernel: 4 steps, TWO samples per thread (ILP-2).
// The dependent gather chain (knot line -> search -> chunk lines) is memory-
// latency-bound; two independent z-chains per thread double MLP per wave.
// Per step: issue both chains' knot loads, do the LDS-only dim-0 evals while
// they are in flight, then search + chunk-gather + eval dim-1.
__global__ __launch_bounds__(256) void k_main(const float* __restrict__ x,
                                              float* __restrict__ out) {
  __shared__ __attribute__((aligned(16))) float kn0[REC];
  for (int j = threadIdx.x; j < REC; j += 256) kn0[j] = g_knots0[j];
  __syncthreads();
  float kf0[16];
  {
    uint4 q0 = *(const uint4*)(kn0);
    uint4 q1 = *(const uint4*)(kn0 + 4);
    unpack8(q0, kf0);
    unpack8(q1, kf0 + 8);
  }
  const int ia = blockIdx.x * 512 + threadIdx.x;
  const int ib = ia + 256;
  const float2 xa = ((const float2*)x)[ia];
  const float2 xb = ((const float2*)x)[ib];
  float z0a = xa.x, z1a = xa.y;
  float z0b = xb.x, z1b = xb.y;
  ((float2*)out)[ia] = xa;  // step 0 = input
  ((float2*)out)[ib] = xb;
  for (int t = 0; t < 4; t++) {
    // ---- issue dim-1 knot loads for BOTH chains ----
    float tta = (z0a - U_LO) * INV_DELTA;
    float ttb = (z0b - U_LO) * INV_DELTA;
    int i0a = min(max((int)floorf(tta), 0), M_GRID - 2);
    int i0b = min(max((int)floorf(ttb), 0), M_GRID - 2);
    float fa = fminf(fmaxf(tta - (float)i0a, 0.0f), 1.0f);
    float fb = fminf(fmaxf(ttb - (float)i0b, 0.0f), 1.0f);
    const float* ra = g_table + (size_t)i0a * REC;
    const float* rb = g_table + (size_t)i0b * REC;
    uint4 qa0 = *(const uint4*)(ra);
    uint4 qa1 = *(const uint4*)(ra + 4);
    uint4 qb0 = *(const uint4*)(rb);
    uint4 qb1 = *(const uint4*)(rb + 4);
    // ---- dim-0 evals (LDS + VALU only) hide the global knot latency ----
    float z0na = dim0_eval(z0a, kn0, kf0);
    float z0nb = dim0_eval(z0b, kn0, kf0);
    // ---- dim-1 search + chunk gathers + eval (two independent chains) ----
    float z1na = dim1_eval(z1a, ra, fa, qa0, qa1);
    float z1nb = dim1_eval(z1b, rb, fb, qb0, qb1);
    z0a = z0na; z1a = z1na;
    z0b = z0nb; z1b = z1nb;
    float2* dst = (float2*)(out + (size_t)(t + 1) * (N_SAMPLES * 2));
    dst[ia] = make_float2(z0a, z1a);
    dst[ib] = make_float2(z0b, z1b);
  }
}

extern "C" void kernel_launch(void* const* d_in, const int* in_sizes, int n_in,
                              void* d_out, int out_size, void* d_ws, size_t ws_size,
                              hipStream_t stream) {
  const float* x  = (const float*)d_in[0];
  const float* W1 = (const float*)d_in[1];
  const float* b1 = (const float*)d_in[2];
  const float* W2 = (const float*)d_in[3];
  const float* b2 = (const float*)d_in[4];
  const float* W3 = (const float*)d_in[5];
  const float* b3 = (const float*)d_in[6];
  float* out = (float*)d_out;
  hipLaunchKernelGGL(k_gemm2, dim3(M_GRID / 32, 4), dim3(256), 0, stream, W1, b1, W2, b2);
  hipLaunchKernelGGL(k_gemm3proc, dim3(M_GRID / MT3), dim3(256), 0, stream, W3, b3);
  hipLaunchKernelGGL(k_main, dim3(N_SAMPLES / 512), dim3(256), 0, stream, x, out);
}

// Round 7
// 91.055 us; speedup vs baseline: 1.0159x; 1.0159x over previous
//
#include <hip/hip_runtime.h>
#include <hip/hip_fp16.h>
#include <math.h>

#define N_SAMPLES 131072
#define HIDDEN    256
#define M_GRID    2048
#define REC       72           // floats per table record (288B; 16B-aligned)
#define U_LO      (-8.0f)
#define DELTA     0.0078125f   // 16 / 2048
#define INV_DELTA 128.0f
#define MT3       8            // m-tile of the layer-3 kernel (256 blocks)
#define STR2      69           // dword stride of packed fp16 weight tiles

// Record layout (72 floats / 288 B):
//   float ofs 0..7  : 16 fp16 knots cw[0..15]  (search-only; cw[16]=5 implicit)
//   float ofs 8+4k  : uint4 chunk k = {h2(ch[k],ch[k+1]), h2(dv[k],dv[k+1]),
//                                      h2(lam[k],cw[k]),  h2(cw[k+1],0)}
__device__ __attribute__((aligned(16))) float g_H2T[M_GRID * HIDDEN];  // [m][k], 2 MB
__device__ __attribute__((aligned(16))) float g_table[M_GRID * REC];   // 576 KB
__device__ __attribute__((aligned(16))) float g_knots0[REC];

__device__ __forceinline__ float rcpf(float x) { return __builtin_amdgcn_rcpf(x); }

__device__ __forceinline__ float softplusf(float x) {
  return fmaxf(x, 0.0f) + log1pf(expf(-fabsf(x)));
}

__device__ __forceinline__ unsigned int packh2(float a, float b) {
  __half2 h = __floats2half2_rn(a, b);
  return *(unsigned int*)&h;
}

__device__ __forceinline__ void unpack8(uint4 u, float* f) {
  float2 t;
  t = __half22float2(*(__half2*)&u.x); f[0] = t.x; f[1] = t.y;
  t = __half22float2(*(__half2*)&u.y); f[2] = t.x; f[3] = t.y;
  t = __half22float2(*(__half2*)&u.z); f[4] = t.x; f[5] = t.y;
  t = __half22float2(*(__half2*)&u.w); f[6] = t.x; f[7] = t.y;
}

// 16-lane-parallel spline-param processing (lane kl of a 16-lane group = bin kl).
__device__ __forceinline__ void process16(float wv, float hv, float dvr,
                                          float lamv, int kl,
                                          float* __restrict__ rec) {
  // ---- widths: softmax + prefix -> cw[kl], cw[kl+1] ----
  float mx = wv;
#pragma unroll
  for (int d = 1; d < 16; d <<= 1) mx = fmaxf(mx, __shfl_xor(mx, d, 16));
  float v = expf(wv - mx);
  float s = v;
#pragma unroll
  for (int d = 1; d < 16; d <<= 1) s += __shfl_xor(s, d, 16);
  float inc = fmaf(v, 0.984f * rcpf(s), 0.001f);
  float cum = inc;
#pragma unroll
  for (int d = 1; d < 16; d <<= 1) {
    float n = __shfl_up(cum, d, 16);
    if (kl >= d) cum += n;
  }
  float cwk1 = (kl == 15) ? 5.0f : fmaf(cum, 10.0f, -5.0f);
  float cwk = __shfl_up(cwk1, 1, 16);
  if (kl == 0) cwk = -5.0f;
  // ---- heights ----
  float mh = hv;
#pragma unroll
  for (int d = 1; d < 16; d <<= 1) mh = fmaxf(mh, __shfl_xor(mh, d, 16));
  float vh = expf(hv - mh);
  float sh = vh;
#pragma unroll
  for (int d = 1; d < 16; d <<= 1) sh += __shfl_xor(sh, d, 16);
  float inch = fmaf(vh, 0.984f * rcpf(sh), 0.001f);
  float cumh = inch;
#pragma unroll
  for (int d = 1; d < 16; d <<= 1) {
    float n = __shfl_up(cumh, d, 16);
    if (kl >= d) cumh += n;
  }
  float chk1 = (kl == 15) ? 5.0f : fmaf(cumh, 10.0f, -5.0f);
  float chk = __shfl_up(chk1, 1, 16);
  if (kl == 0) chk = -5.0f;
  // ---- derivatives (boundary = 1) ----
  float dvk1 = (kl < 15) ? (0.001f + softplusf(dvr)) : 1.0f;
  float dvk = __shfl_up(dvk1, 1, 16);
  if (kl == 0) dvk = 1.0f;
  // ---- lambda ----
  float lm = fmaf(0.95f, 1.0f / (1.0f + expf(-lamv)), 0.025f);
  // ---- emit chunk kl ----
  uint4 ck = make_uint4(packh2(chk, chk1), packh2(dvk, dvk1),
                        packh2(lm, cwk), packh2(cwk1, 0.0f));
  ((uint4*)rec)[2 + kl] = ck;
  // ---- knot row: dword q = h2(cw[2q], cw[2q+1]), lanes 0..7 ----
  float cA = __shfl(cwk, 2 * kl, 16);
  float cB = __shfl(cwk, 2 * kl + 1, 16);
  if (kl < 8) ((unsigned int*)rec)[kl] = packh2(cA, cB);
}

// Monotonic linear-rational spline (approx rcp/sqrt; tol 0.099 >> 1ulp).
__device__ __forceinline__ float spline_eval(float z, float xk, float xk1,
                                             float yk, float yk1,
                                             float dk, float dk1, float lam) {
  float xc = fminf(fmaxf(z, -5.0f), 5.0f);
  float wk = xk1 - xk;
  float hk = yk1 - yk;
  float wb = __builtin_amdgcn_sqrtf(dk * rcpf(dk1));
  float wc = fmaf(lam, dk, (1.0f - lam) * wb * dk1) * wk * rcpf(hk);
  float ya = yk;
  float yb = yk + hk;
  float yc = fmaf(lam * wb, yb, (1.0f - lam) * ya) * rcpf(fmaf(lam, wb, 1.0f - lam));
  float th = (xc - xk) * rcpf(wk);
  bool left = th <= lam;
  float num = left ? fmaf(ya, lam - th, wc * yc * th)
                   : fmaf(wc * yc, 1.0f - th, wb * yb * (th - lam));
  float den = left ? fmaf(wc, th, lam - th)
                   : fmaf(wc, 1.0f - th, wb * (th - lam));
  float y = num * rcpf(den);
  bool inside = (z >= -5.0f) && (z <= 5.0f);
  return inside ? y : z;
}

// ---------------- Layer-2 GEMM: H2T[m][o] = relu(sum_k W2[o][k]*h_k(u_m) + b2[o])
__global__ __launch_bounds__(256) void k_gemm2(const float* __restrict__ W1,
                                               const float* __restrict__ b1,
                                               const float* __restrict__ W2,
                                               const float* __restrict__ b2) {
  __shared__ unsigned int sW[128 * STR2];  // 35.3 KB
  __shared__ float2 sAB[256];              // 2 KB
  __shared__ float red[3 * 64 * 36];       // 27.6 KB
  const int t = threadIdx.x;
  const int m0 = blockIdx.x * 32;
  const int o0 = blockIdx.y * 64;
  {
    const int ol = t >> 2, seg = t & 3;
    const float* src = W2 + (size_t)(o0 + ol) * 256 + 16 * seg;
#pragma unroll
    for (int c = 0; c < 4; c++) {
#pragma unroll
      for (int q = 0; q < 4; q++) {
        float4 v = *(const float4*)(src + 64 * c + 4 * q);
        const int k2 = (64 * c + 16 * seg + 4 * q) >> 1;
        sW[(k2 + 0) * STR2 + ol] = packh2(v.x, v.y);
        sW[(k2 + 1) * STR2 + ol] = packh2(v.z, v.w);
      }
    }
  }
  sAB[t] = make_float2(W1[2 * t], b1[t]);
  __syncthreads();
  const int w = t >> 6, lane = t & 63;
  const int tp = lane >> 2, tm = lane & 3;
  const float u0 = fmaf((float)(m0 + 8 * tm), DELTA, U_LO);
  float acc[4][8] = {};
  const int kb2 = w * 32;
#pragma unroll 4
  for (int kk = 0; kk < 32; kk++) {
    const int k2 = kb2 + kk;
    uint4 ap = *(const uint4*)&sW[k2 * STR2 + 4 * tp];
    float2 a0 = __half22float2(*(__half2*)&ap.x);
    float2 a1 = __half22float2(*(__half2*)&ap.y);
    float2 a2 = __half22float2(*(__half2*)&ap.z);
    float2 a3 = __half22float2(*(__half2*)&ap.w);
    float2 abe = sAB[2 * k2];
    float2 abo = sAB[2 * k2 + 1];
    float t0e = fmaf(abe.x, u0, abe.y), ste = abe.x * DELTA;
    float t0o = fmaf(abo.x, u0, abo.y), sto = abo.x * DELTA;
    float he[8], ho[8];
#pragma unroll
    for (int j = 0; j < 8; j++) {
      he[j] = fmaxf(fmaf((float)j, ste, t0e), 0.0f);
      ho[j] = fmaxf(fmaf((float)j, sto, t0o), 0.0f);
    }
#pragma unroll
    for (int j = 0; j < 8; j++) {
      acc[0][j] = fmaf(a0.x, he[j], acc[0][j]);
      acc[1][j] = fmaf(a1.x, he[j], acc[1][j]);
      acc[2][j] = fmaf(a2.x, he[j], acc[2][j]);
      acc[3][j] = fmaf(a3.x, he[j], acc[3][j]);
      acc[0][j] = fmaf(a0.y, ho[j], acc[0][j]);
      acc[1][j] = fmaf(a1.y, ho[j], acc[1][j]);
      acc[2][j] = fmaf(a2.y, ho[j], acc[2][j]);
      acc[3][j] = fmaf(a3.y, ho[j], acc[3][j]);
    }
  }
  if (w > 0) {
#pragma unroll
    for (int i = 0; i < 4; i++) {
      *(float4*)&red[((w - 1) * 64 + lane) * 36 + 8 * i] =
          make_float4(acc[i][0], acc[i][1], acc[i][2], acc[i][3]);
      *(float4*)&red[((w - 1) * 64 + lane) * 36 + 8 * i + 4] =
          make_float4(acc[i][4], acc[i][5], acc[i][6], acc[i][7]);
    }
  }
  __syncthreads();
  if (w == 0) {
#pragma unroll
    for (int v = 0; v < 3; v++) {
#pragma unroll
      for (int i = 0; i < 4; i++) {
        float4 r0 = *(const float4*)&red[(v * 64 + lane) * 36 + 8 * i];
        float4 r1 = *(const float4*)&red[(v * 64 + lane) * 36 + 8 * i + 4];
        acc[i][0] += r0.x; acc[i][1] += r0.y; acc[i][2] += r0.z; acc[i][3] += r0.w;
        acc[i][4] += r1.x; acc[i][5] += r1.y; acc[i][6] += r1.z; acc[i][7] += r1.w;
      }
    }
    float4 bb = *(const float4*)&b2[o0 + 4 * tp];
#pragma unroll
    for (int j = 0; j < 8; j++) {
      float4 r;
      r.x = fmaxf(acc[0][j] + bb.x, 0.0f);
      r.y = fmaxf(acc[1][j] + bb.y, 0.0f);
      r.z = fmaxf(acc[2][j] + bb.z, 0.0f);
      r.w = fmaxf(acc[3][j] + bb.w, 0.0f);
      *(float4*)&g_H2T[(size_t)(m0 + 8 * tm + j) * 256 + o0 + 4 * tp] = r;
    }
  }
}

// ---------------- Layer-3 GEMM (odd rows of W3) + PARALLEL param processing
__global__ __launch_bounds__(256) void k_gemm3proc(const float* __restrict__ W3,
                                                   const float* __restrict__ b3) {
  __shared__ unsigned int sW[128 * STR2];  // 35.3 KB packed W3odd^T [k2][p]
  __shared__ unsigned int sH[128 * 9];     // 4.6 KB packed H2 slice [k2][m]
  __shared__ float red[3 * 64 * 8];        // 6 KB wave partials
  __shared__ float raws[64 * 9];           // 2.3 KB [p][m]
  const int t = threadIdx.x;
  const int m0 = blockIdx.x * MT3;
  {
    const int ol = t >> 2, seg = t & 3;
    const int row = (ol < 63) ? (2 * ol + 1) : 1;
    const float* src = W3 + (size_t)row * 256 + 16 * seg;
#pragma unroll
    for (int c = 0; c < 4; c++) {
#pragma unroll
      for (int q = 0; q < 4; q++) {
        float4 v = *(const float4*)(src + 64 * c + 4 * q);
        const int k2 = (64 * c + 16 * seg + 4 * q) >> 1;
        sW[(k2 + 0) * STR2 + ol] = packh2(v.x, v.y);
        sW[(k2 + 1) * STR2 + ol] = packh2(v.z, v.w);
      }
    }
  }
  {
    const int j = t & 7, c = t >> 3;
    const float* src = g_H2T + (size_t)(m0 + j) * 256 + 8 * c;
    float4 f0 = *(const float4*)(src);
    float4 f1 = *(const float4*)(src + 4);
    sH[(4 * c + 0) * 9 + j] = packh2(f0.x, f0.y);
    sH[(4 * c + 1) * 9 + j] = packh2(f0.z, f0.w);
    sH[(4 * c + 2) * 9 + j] = packh2(f1.x, f1.y);
    sH[(4 * c + 3) * 9 + j] = packh2(f1.z, f1.w);
  }
  __syncthreads();
  const int w = t >> 6, lane = t & 63;
  const int tp = lane >> 2, tm = lane & 3;
  float acc[4][2] = {};
  const int kb2 = w * 32;
#pragma unroll 4
  for (int kk = 0; kk < 32; kk++) {
    const int k2 = kb2 + kk;
    uint4 ap = *(const uint4*)&sW[k2 * STR2 + 4 * tp];
    uint2 bp = *(const uint2*)&sH[k2 * 9 + 2 * tm];
    float2 a0 = __half22float2(*(__half2*)&ap.x);
    float2 a1 = __half22float2(*(__half2*)&ap.y);
    float2 a2 = __half22float2(*(__half2*)&ap.z);
    float2 a3 = __half22float2(*(__half2*)&ap.w);
    float2 b0 = __half22float2(*(__half2*)&bp.x);
    float2 b1v = __half22float2(*(__half2*)&bp.y);
    float ae[4] = {a0.x, a1.x, a2.x, a3.x};
    float ao[4] = {a0.y, a1.y, a2.y, a3.y};
#pragma unroll
    for (int i = 0; i < 4; i++) {
      acc[i][0] = fmaf(ae[i], b0.x, acc[i][0]);
      acc[i][0] = fmaf(ao[i], b0.y, acc[i][0]);
      acc[i][1] = fmaf(ae[i], b1v.x, acc[i][1]);
      acc[i][1] = fmaf(ao[i], b1v.y, acc[i][1]);
    }
  }
  // (no barrier needed here: red is a distinct buffer; the barrier below
  //  orders the w>0 writes against the w==0 reads)
  if (w > 0) {
#pragma unroll
    for (int i = 0; i < 4; i++) {
      red[((w - 1) * 64 + lane) * 8 + 2 * i + 0] = acc[i][0];
      red[((w - 1) * 64 + lane) * 8 + 2 * i + 1] = acc[i][1];
    }
  }
  __syncthreads();
  if (w == 0) {
#pragma unroll
    for (int v = 0; v < 3; v++) {
#pragma unroll
      for (int i = 0; i < 4; i++) {
        acc[i][0] += red[(v * 64 + lane) * 8 + 2 * i + 0];
        acc[i][1] += red[(v * 64 + lane) * 8 + 2 * i + 1];
      }
    }
#pragma unroll
    for (int i = 0; i < 4; i++) {
      const int p = 4 * tp + i;
      const int bi = (p < 63) ? (2 * p + 1) : 1;
      const float bias = b3[bi];
      raws[p * 9 + 2 * tm + 0] = acc[i][0] + bias;
      raws[p * 9 + 2 * tm + 1] = acc[i][1] + bias;
    }
  }
  __syncthreads();
  if (t < 128) {
    const int c = t >> 4, kl = t & 15;
    float wv = raws[kl * 9 + c];
    float hv = raws[(16 + kl) * 9 + c];
    float dvr = raws[(32 + kl) * 9 + c];
    float lamv = raws[(47 + kl) * 9 + c];
    process16(wv, hv, dvr, lamv, kl, g_table + (size_t)(m0 + c) * REC);
  } else if (blockIdx.x == 0 && (t >> 4) == 8) {
    const int kl = t & 15;
    float wv = b3[2 * kl];
    float hv = b3[2 * (16 + kl)];
    float dvr = b3[2 * (32 + kl)];
    float lamv = b3[2 * (47 + kl)];
    process16(wv, hv, dvr, lamv, kl, g_knots0);
  }
}

// ---------------- Main flow kernel: 4 steps, ONE sample per thread.
// (Round-5 configuration restored: ILP-2 measured neutral-to-negative --
//  the kernel is TLP-rich at 512 blocks and the dual chains share one
//  vmcnt queue, so no extra memory-level parallelism was realized.)
__global__ __launch_bounds__(256) void k_main(const float* __restrict__ x,
                                              float* __restrict__ out) {
  __shared__ __attribute__((aligned(16))) float kn0[REC];
  for (int j = threadIdx.x; j < REC; j += 256) kn0[j] = g_knots0[j];
  __syncthreads();
  float kf0[16];
  {
    uint4 q0 = *(const uint4*)(kn0);
    uint4 q1 = *(const uint4*)(kn0 + 4);
    unpack8(q0, kf0);
    unpack8(q1, kf0 + 8);
  }
  const int i = blockIdx.x * 256 + threadIdx.x;
  const float2 xv = ((const float2*)x)[i];
  float z0 = xv.x, z1 = xv.y;
  ((float2*)out)[i] = xv;  // step 0 = input
  for (int t = 0; t < 4; t++) {
    float tt = (z0 - U_LO) * INV_DELTA;
    int i0 = (int)floorf(tt);
    i0 = min(max(i0, 0), M_GRID - 2);
    float f = fminf(fmaxf(tt - (float)i0, 0.0f), 1.0f);
    const float* r0 = g_table + (size_t)i0 * REC;
    float kf[16];
    {
      uint4 q0 = *(const uint4*)(r0);
      uint4 q1 = *(const uint4*)(r0 + 4);
      unpack8(q0, kf);
      unpack8(q1, kf + 8);
    }
    float xc1 = fminf(fmaxf(z1, -5.0f), 5.0f);
    int k1 = 0;
#pragma unroll
    for (int j = 1; j < 16; j++) k1 += (xc1 >= kf[j]) ? 1 : 0;
    const float* c0 = r0 + 8 + 4 * k1;
    uint4 A = *(const uint4*)c0;
    uint4 B = *(const uint4*)(c0 + REC);
    float2 Ay = __half22float2(*(__half2*)&A.x);
    float2 Ad = __half22float2(*(__half2*)&A.y);
    float2 Al = __half22float2(*(__half2*)&A.z);
    float2 Ax = __half22float2(*(__half2*)&A.w);
    float2 By = __half22float2(*(__half2*)&B.x);
    float2 Bd = __half22float2(*(__half2*)&B.y);
    float2 Bl = __half22float2(*(__half2*)&B.z);
    float2 Bx = __half22float2(*(__half2*)&B.w);
    float yk  = fmaf(f, By.x - Ay.x, Ay.x);
    float yk1 = fmaf(f, By.y - Ay.y, Ay.y);
    float dk  = fmaf(f, Bd.x - Ad.x, Ad.x);
    float dk1 = fmaf(f, Bd.y - Ad.y, Ad.y);
    float lam = fmaf(f, Bl.x - Al.x, Al.x);
    float xk  = fmaf(f, Bl.y - Al.y, Al.y);
    float xk1 = fmaf(f, Bx.x - Ax.x, Ax.x);
    float z1n = spline_eval(z1, xk, xk1, yk, yk1, dk, dk1, lam);
    float xc0 = fminf(fmaxf(z0, -5.0f), 5.0f);
    int k0 = 0;
#pragma unroll
    for (int j = 1; j < 16; j++) k0 += (xc0 >= kf0[j]) ? 1 : 0;
    uint4 C = *(const uint4*)&kn0[8 + 4 * k0];
    float2 Cy = __half22float2(*(__half2*)&C.x);
    float2 Cd = __half22float2(*(__half2*)&C.y);
    float2 Cl = __half22float2(*(__half2*)&C.z);
    float2 Cx = __half22float2(*(__half2*)&C.w);
    float z0n = spline_eval(z0, Cl.y, Cx.x, Cy.x, Cy.y, Cd.x, Cd.y, Cl.x);
    z0 = z0n; z1 = z1n;
    ((float2*)(out + (size_t)(t + 1) * (N_SAMPLES * 2)))[i] = make_float2(z0, z1);
  }
}

extern "C" void kernel_launch(void* const* d_in, const int* in_sizes, int n_in,
                              void* d_out, int out_size, void* d_ws, size_t ws_size,
                              hipStream_t stream) {
  const float* x  = (const float*)d_in[0];
  const float* W1 = (const float*)d_in[1];
  const float* b1 = (const float*)d_in[2];
  const float* W2 = (const float*)d_in[3];
  const float* b2 = (const float*)d_in[4];
  const float* W3 = (const float*)d_in[5];
  const float* b3 = (const float*)d_in[6];
  float* out = (float*)d_out;
  hipLaunchKernelGGL(k_gemm2, dim3(M_GRID / 32, 4), dim3(256), 0, stream, W1, b1, W2, b2);
  hipLaunchKernelGGL(k_gemm3proc, dim3(M_GRID / MT3), dim3(256), 0, stream, W3, b3);
  hipLaunchKernelGGL(k_main, dim3(N_SAMPLES / 256), dim3(256), 0, stream, x, out);
}